// Round 5
// baseline (363.907 us; speedup 1.0000x reference)
//
#include <hip/hip_runtime.h>
#include <math.h>

#define BATCH 8
#define SEQL 4096
#define DMODEL 512
#define SDIM 64
#define MROWS (BATCH * SEQL)  // 32768
#define LN_EPS 1e-5f

typedef __attribute__((ext_vector_type(8))) short bf16x8;
typedef __attribute__((ext_vector_type(4))) float f32x4;

// ---------- helpers ----------
__device__ __forceinline__ float wave_sum(float v) {
#pragma unroll
  for (int off = 32; off > 0; off >>= 1) v += __shfl_xor(v, off, 64);
  return v;
}

__device__ __forceinline__ unsigned short f2bf(float f) {  // RNE float->bf16
  unsigned int u = __float_as_uint(f);
  u += 0x7fffu + ((u >> 16) & 1u);
  return (unsigned short)(u >> 16);
}

// fast erf-based gelu (Abramowitz-Stegun 7.1.26, |erf err| <= 1.5e-7)
__device__ __forceinline__ float gelu_fast(float v) {
  float s = v * 0.70710678118654752f;
  float ax = fabsf(s);
  float t = 1.0f / (1.0f + 0.3275911f * ax);
  float p = ((((1.061405429f * t - 1.453152027f) * t + 1.421413741f) * t - 0.284496736f) * t +
             0.254829592f) *
            t;
  float er = 1.0f - p * __expf(-ax * ax);
  er = copysignf(er, s);
  return 0.5f * v * (1.0f + er);
}

__device__ __forceinline__ void gl2lds16(const void* g, void* l) {
  // async global->LDS, 16B/lane; LDS dest = wave-uniform base + lane*16
  __builtin_amdgcn_global_load_lds((const __attribute__((address_space(1))) void*)g,
                                   (__attribute__((address_space(3))) void*)l, 16, 0, 0);
}

// ---------- K1: LN1 stats for x (mu, rstd per row) + bf16 cast of x ----------
__global__ void ln_stats_kernel(const float* __restrict__ x, float* __restrict__ mu,
                                float* __restrict__ rstd, unsigned short* __restrict__ xbf) {
  int row = blockIdx.x * 4 + (threadIdx.x >> 6);
  int lane = threadIdx.x & 63;
  const float4* xp = (const float4*)(x + (size_t)row * DMODEL);
  float4 a = xp[lane * 2];
  float4 b = xp[lane * 2 + 1];
  float s = a.x + a.y + a.z + a.w + b.x + b.y + b.z + b.w;
  float q = a.x * a.x + a.y * a.y + a.z * a.z + a.w * a.w + b.x * b.x + b.y * b.y +
            b.z * b.z + b.w * b.w;
  s = wave_sum(s);
  q = wave_sum(q);
  uint4 pk;
  pk.x = (unsigned)f2bf(a.x) | ((unsigned)f2bf(a.y) << 16);
  pk.y = (unsigned)f2bf(a.z) | ((unsigned)f2bf(a.w) << 16);
  pk.z = (unsigned)f2bf(b.x) | ((unsigned)f2bf(b.y) << 16);
  pk.w = (unsigned)f2bf(b.z) | ((unsigned)f2bf(b.w) << 16);
  ((uint4*)(xbf + (size_t)row * DMODEL))[lane] = pk;
  if (lane == 0) {
    float m = s * (1.0f / DMODEL);
    float var = q * (1.0f / DMODEL) - m * m;
    mu[row] = m;
    rstd[row] = rsqrtf(var + LN_EPS);
  }
}

// ---------- prep: all weight transposes + B-prep in ONE kernel ----------
__device__ __forceinline__ void transpose_body(const float* __restrict__ W,
                                               unsigned short* __restrict__ Wt, int K, int N,
                                               int bx, int by,
                                               unsigned short (*tile)[65]) {
  int k0 = by * 64, n0 = bx * 64;
  int tx = threadIdx.x & 15, ty = threadIdx.x >> 4;
#pragma unroll
  for (int p = 0; p < 4; ++p) {
    int k = p * 16 + ty;
    float4 v = *(const float4*)&W[(size_t)(k0 + k) * N + n0 + tx * 4];
    tile[tx * 4 + 0][k] = f2bf(v.x);
    tile[tx * 4 + 1][k] = f2bf(v.y);
    tile[tx * 4 + 2][k] = f2bf(v.z);
    tile[tx * 4 + 3][k] = f2bf(v.w);
  }
  __syncthreads();
#pragma unroll
  for (int p = 0; p < 4; ++p) {
    int n = p * 16 + ty;
    ushort4 o;
    o.x = tile[n][tx * 4 + 0];
    o.y = tile[n][tx * 4 + 1];
    o.z = tile[n][tx * 4 + 2];
    o.w = tile[n][tx * 4 + 3];
    *(ushort4*)&Wt[(size_t)(n0 + n) * K + k0 + tx * 4] = o;
  }
}

__global__ __launch_bounds__(256) void prep_all_kernel(
    const float* __restrict__ W1, const float* __restrict__ W2, const float* __restrict__ Cm,
    const float* __restrict__ Bm, const float* __restrict__ gamma,
    const float* __restrict__ beta, unsigned short* __restrict__ w1t,
    unsigned short* __restrict__ w2t, unsigned short* __restrict__ ctb,
    unsigned short* __restrict__ Bgt, float* __restrict__ gB, float* __restrict__ bB) {
  __shared__ unsigned short tile[64][65];
  int b = blockIdx.x;
  if (b < 128) {  // W1 [512][1024] -> w1t [1024][512]
    transpose_body(W1, w1t, 512, 1024, b & 15, b >> 4, tile);
  } else if (b < 256) {  // W2 [1024][512] -> w2t [512][1024]
    transpose_body(W2, w2t, 1024, 512, (b - 128) & 7, (b - 128) >> 3, tile);
  } else if (b < 264) {  // Cm [64][512] -> ctb [512][64]
    transpose_body(Cm, ctb, 64, 512, b - 256, 0, tile);
  } else {  // Bgt[s][d]=bf16(gamma[d]*B[d][s]); gB[s]=gamma@B; bB[s]=beta@B
    int s = (b - 264) * 4 + (threadIdx.x >> 6);
    int l = threadIdx.x & 63;
    float gs = 0.0f, bs = 0.0f;
    unsigned short tmp[8];
#pragma unroll
    for (int u = 0; u < 8; ++u) {
      int d = l * 8 + u;
      float bv = Bm[(size_t)d * SDIM + s];
      float gv = gamma[d], ev = beta[d];
      gs += gv * bv;
      bs += ev * bv;
      tmp[u] = f2bf(gv * bv);
    }
    *(ushort4*)&Bgt[(size_t)s * DMODEL + l * 8] = make_ushort4(tmp[0], tmp[1], tmp[2], tmp[3]);
    *(ushort4*)&Bgt[(size_t)s * DMODEL + l * 8 + 4] =
        make_ushort4(tmp[4], tmp[5], tmp[6], tmp[7]);
    gs = wave_sum(gs);
    bs = wave_sum(bs);
    if (l == 0) {
      gB[s] = gs;
      bB[s] = bs;
    }
  }
}

// ---------- K2: xB = rstd*(xbf@Bgt) - rstd*mu*gB + bB   (MFMA bf16) ----------
__global__ __launch_bounds__(256) void xb_mfma_kernel(
    const unsigned short* __restrict__ xbf, const unsigned short* __restrict__ Bgt,
    const float* __restrict__ mu, const float* __restrict__ rstd, const float* __restrict__ gB,
    const float* __restrict__ bB, float* __restrict__ xB) {
  __shared__ unsigned short As[128 * 32];  // [m][k]
  __shared__ unsigned short Bs[64 * 32];   // [s][k]
  const int t = threadIdx.x;
  const int wave = t >> 6, lane = t & 63;
  const int m0 = blockIdx.x * 128;
  const int wm = wave * 32;
  const int row = t >> 2, seg = t & 3;
  const int fr = lane & 15, fq = lane >> 4;
  f32x4 acc[2][4] = {};
  for (int k0 = 0; k0 < DMODEL; k0 += 32) {
    __syncthreads();
    gl2lds16(xbf + (size_t)(m0 + row) * DMODEL + k0 + seg * 8, As + (size_t)(wave * 16) * 32);
    gl2lds16(xbf + (size_t)(m0 + 64 + row) * DMODEL + k0 + seg * 8,
             As + (size_t)(64 + wave * 16) * 32);
    gl2lds16(Bgt + (size_t)row * DMODEL + k0 + seg * 8, Bs + (size_t)(wave * 16) * 32);
    __syncthreads();
#pragma unroll
    for (int i = 0; i < 2; ++i) {
      bf16x8 a = *(const bf16x8*)&As[(wm + i * 16 + fr) * 32 + fq * 8];
#pragma unroll
      for (int j = 0; j < 4; ++j) {
        bf16x8 b = *(const bf16x8*)&Bs[(j * 16 + fr) * 32 + fq * 8];
        acc[i][j] = __builtin_amdgcn_mfma_f32_16x16x32_bf16(a, b, acc[i][j], 0, 0, 0);
      }
    }
  }
#pragma unroll
  for (int i = 0; i < 2; ++i)
#pragma unroll
    for (int r = 0; r < 4; ++r) {
      const int m = m0 + wm + i * 16 + fq * 4 + r;
      const float rr = rstd[m], negmurr = -mu[m] * rstd[m];
#pragma unroll
      for (int j = 0; j < 4; ++j) {
        const int s = j * 16 + fr;
        xB[(size_t)m * SDIM + s] = rr * acc[i][j][r] + negmurr * gB[s] + bB[s];
      }
    }
}

// ---------- K3a/b: exact chunked scan h_t = a*h_{t-1} + x_t over L ----------
__global__ void scan_ends_kernel(const float* __restrict__ xB, const float* __restrict__ logA,
                                 const float* __restrict__ logdt, float* __restrict__ ends) {
  int t = blockIdx.x * 128 + threadIdx.x;
  int s = t & 63;
  int c = (t >> 6) & 63;
  int b = t >> 12;
  float a = expf(-expf(logA[s]) * expf(logdt[0]));
  const float* p = xB + ((size_t)(b * SEQL + c * 64)) * SDIM + s;
  float e = 0.0f;
#pragma unroll
  for (int i = 0; i < 64; ++i) e = a * e + p[(size_t)i * SDIM];
  ends[(b * 64 + c) * 64 + s] = e;
}

// carry inlined: each wave (uniform c) recomputes its chunk-entry state from ends (L2-hot)
__global__ void scan_fix_kernel(const float* __restrict__ logA, const float* __restrict__ logdt,
                                const float* __restrict__ ends, const float* __restrict__ xB,
                                unsigned short* __restrict__ hsb) {
  int t = blockIdx.x * 128 + threadIdx.x;
  int s = t & 63;
  int c = (t >> 6) & 63;
  int b = t >> 12;
  float a = expf(-expf(logA[s]) * expf(logdt[0]));
  float a64 = a;
#pragma unroll
  for (int i = 0; i < 6; ++i) a64 *= a64;  // a^64
  float h = 0.0f;
  for (int cp = 0; cp < c; ++cp) h = a64 * h + ends[(b * 64 + cp) * 64 + s];
  const float* p = xB + ((size_t)(b * SEQL + c * 64)) * SDIM + s;
  unsigned short* q = hsb + ((size_t)(b * SEQL + c * 64)) * SDIM + s;
#pragma unroll
  for (int i = 0; i < 64; ++i) {
    h = a * h + p[(size_t)i * SDIM];
    q[(size_t)i * SDIM] = f2bf(h);
  }
}

// ---------- K4: y = hsb@ctb^T + xn*D + x -> out ; then LN(y) -> yn (fused) ----------
// 128 rows x full 512 cols per block, 8 waves (2m x 4n), per-wave 64x128, K=64 one-shot.
__global__ __launch_bounds__(512, 2) void y_ln_fused_kernel(
    const unsigned short* __restrict__ hsb, const unsigned short* __restrict__ ctb,
    const float* __restrict__ x, const float* __restrict__ mu1,
    const float* __restrict__ rstd1, const float* __restrict__ gamma,
    const float* __restrict__ beta, const float* __restrict__ Dv, float* __restrict__ out,
    unsigned short* __restrict__ yn) {
  __shared__ alignas(16) unsigned short As[128 * 64];  // 16 KB, swizzled
  __shared__ alignas(16) unsigned short Bs[512 * 64];  // 64 KB, swizzled
  __shared__ float rsum[128], rsq[128];
  const int t = threadIdx.x;
  const int wid = t >> 6, lane = t & 63;
  const int m0 = blockIdx.x * 128;
  const int wm = (wid >> 2) * 64;   // 0 / 64
  const int wn = (wid & 3) * 128;   // 0..384
  const int fr = lane & 15, fq = lane >> 4;
  const int srow = t >> 3;
  const int ksw = ((t & 7) ^ ((t >> 3) & 7)) << 3;  // pre-swizzled src k-offset
  gl2lds16(hsb + (size_t)(m0 + srow) * 64 + ksw, &As[(wid * 8) * 64]);
  gl2lds16(hsb + (size_t)(m0 + 64 + srow) * 64 + ksw, &As[(64 + wid * 8) * 64]);
#pragma unroll
  for (int h = 0; h < 8; ++h)
    gl2lds16(ctb + (size_t)(h * 64 + srow) * 64 + ksw, &Bs[(h * 64 + wid * 8) * 64]);
  if (t < 128) {
    rsum[t] = 0.0f;
    rsq[t] = 0.0f;
  }
  asm volatile("s_waitcnt vmcnt(0)" ::: "memory");
  __builtin_amdgcn_s_barrier();

  f32x4 acc[4][8] = {};
#pragma unroll
  for (int s = 0; s < 2; ++s) {
    bf16x8 af[4], bf[8];
#pragma unroll
    for (int i = 0; i < 4; ++i)
      af[i] = *(const bf16x8*)&As[(wm + i * 16 + fr) * 64 + ((s * 4 + fq) ^ (fr & 7)) * 8];
#pragma unroll
    for (int j = 0; j < 8; ++j)
      bf[j] = *(const bf16x8*)&Bs[(wn + j * 16 + fr) * 64 + ((s * 4 + fq) ^ (fr & 7)) * 8];
#pragma unroll
    for (int i = 0; i < 4; ++i)
#pragma unroll
      for (int j = 0; j < 8; ++j)
        acc[i][j] = __builtin_amdgcn_mfma_f32_16x16x32_bf16(af[i], bf[j], acc[i][j], 0, 0, 0);
  }

  float ga[8], be[8], dd[8];
#pragma unroll
  for (int j = 0; j < 8; ++j) {
    const int cg = wn + j * 16 + fr;
    ga[j] = gamma[cg];
    be[j] = beta[cg];
    dd[j] = Dv[cg];
  }
  float ps[4][4], pq[4][4];
#pragma unroll
  for (int i = 0; i < 4; ++i)
#pragma unroll
    for (int r = 0; r < 4; ++r) {
      const int m = m0 + wm + i * 16 + fq * 4 + r;
      const float mu = mu1[m], rs = rstd1[m];
      float s1 = 0.0f, s2 = 0.0f;
#pragma unroll
      for (int j = 0; j < 8; ++j) {
        const int cg = wn + j * 16 + fr;
        const float xv = x[(size_t)m * DMODEL + cg];
        float yv = acc[i][j][r] + ((xv - mu) * rs * ga[j] + be[j]) * dd[j] + xv;
        out[(size_t)m * DMODEL + cg] = yv;
        acc[i][j][r] = yv;
        s1 += yv;
        s2 += yv * yv;
      }
      ps[i][r] = s1;
      pq[i][r] = s2;
    }
#pragma unroll
  for (int i = 0; i < 4; ++i)
#pragma unroll
    for (int r = 0; r < 4; ++r) {
#pragma unroll
      for (int off = 1; off < 16; off <<= 1) {
        ps[i][r] += __shfl_xor(ps[i][r], off, 64);
        pq[i][r] += __shfl_xor(pq[i][r], off, 64);
      }
    }
  if (fr == 0) {
#pragma unroll
    for (int i = 0; i < 4; ++i)
#pragma unroll
      for (int r = 0; r < 4; ++r) {
        atomicAdd(&rsum[wm + i * 16 + fq * 4 + r], ps[i][r]);
        atomicAdd(&rsq[wm + i * 16 + fq * 4 + r], pq[i][r]);
      }
  }
  __syncthreads();
#pragma unroll
  for (int i = 0; i < 4; ++i)
#pragma unroll
    for (int r = 0; r < 4; ++r) {
      const int rl = wm + i * 16 + fq * 4 + r;
      const int m = m0 + rl;
      const float mu2 = rsum[rl] * (1.0f / DMODEL);
      const float var = rsq[rl] * (1.0f / DMODEL) - mu2 * mu2;
      const float rs2 = rsqrtf(var + LN_EPS);
#pragma unroll
      for (int j = 0; j < 8; ++j) {
        const int cg = wn + j * 16 + fr;
        yn[(size_t)m * DMODEL + cg] = f2bf((acc[i][j][r] - mu2) * rs2 * ga[j] + be[j]);
      }
    }
}

// ---------- 128x128-tile, BK=64, 4-wave, SINGLE-BUFFER, 4-blocks/CU GEMM ----------
// Occupancy-based latency hiding (m97 pattern): 32 KB LDS + launch_bounds(256,4) ->
// 4 co-resident blocks (16 waves/CU). Each block's stage->vmcnt(0)->barrier drain and
// its epilogue overlap the other 3 blocks' MFMA. No double-buffer: residency IS the
// pipeline. Four prior schedule variants at 1-2 blocks/CU all pinned at ~21% MfmaUtil.
template <int K, int NALL, int EPI>
__global__ __launch_bounds__(256, 4) void gemm128_kernel(
    const unsigned short* __restrict__ Am, const unsigned short* __restrict__ Bm,
    const float* __restrict__ bias, unsigned short* __restrict__ gout,
    float* __restrict__ out) {
  __shared__ alignas(16) unsigned short As[128 * 64];  // 16 KB
  __shared__ alignas(16) unsigned short Bs[128 * 64];  // 16 KB
  const int t = threadIdx.x;
  const int wid = t >> 6, lane = t & 63;
  // bijective XCD-aware swizzle (nwg % 8 == 0 for both launches)
  const int nwg = gridDim.x * gridDim.y;
  const int orig = blockIdx.y * gridDim.x + blockIdx.x;
  const int swz = (orig & 7) * (nwg >> 3) + (orig >> 3);
  const int m0 = (swz / gridDim.x) * 128, n0 = (swz % gridDim.x) * 128;
  const int wm = (wid >> 1) * 64, wn = (wid & 1) * 64;
  const int fr = lane & 15, fq = lane >> 4;
  constexpr int NT = K / 64;
  const int srow = t >> 3;                          // 0..31
  const int ksw = ((t & 7) ^ ((t >> 3) & 7)) << 3;  // pre-swizzled src k-offset (elems)

  auto stageA = [&](int kt) {
    const unsigned short* s0 = Am + (size_t)(m0 + srow) * K + kt * 64 + ksw;
#pragma unroll
    for (int q = 0; q < 4; ++q)
      gl2lds16(s0 + (size_t)(q * 32) * K, &As[(q * 32 + wid * 8) * 64]);
  };
  auto stageB = [&](int kt) {
    const unsigned short* s0 = Bm + (size_t)(n0 + srow) * K + kt * 64 + ksw;
#pragma unroll
    for (int q = 0; q < 4; ++q)
      gl2lds16(s0 + (size_t)(q * 32) * K, &Bs[(q * 32 + wid * 8) * 64]);
  };

  f32x4 acc[4][4] = {};
  for (int c = 0; c < NT; ++c) {
    stageA(c);
    stageB(c);
    asm volatile("s_waitcnt vmcnt(0)" ::: "memory");
    __builtin_amdgcn_s_barrier();
    __builtin_amdgcn_sched_barrier(0);
    bf16x8 av[2][4], bv[2][4];
#pragma unroll
    for (int s = 0; s < 2; ++s) {
#pragma unroll
      for (int i = 0; i < 4; ++i)
        av[s][i] =
            *(const bf16x8*)&As[(wm + i * 16 + fr) * 64 + ((s * 4 + fq) ^ (fr & 7)) * 8];
#pragma unroll
      for (int j = 0; j < 4; ++j)
        bv[s][j] =
            *(const bf16x8*)&Bs[(wn + j * 16 + fr) * 64 + ((s * 4 + fq) ^ (fr & 7)) * 8];
    }
    __builtin_amdgcn_s_setprio(1);
#pragma unroll
    for (int s = 0; s < 2; ++s)
#pragma unroll
      for (int i = 0; i < 4; ++i)
#pragma unroll
        for (int j = 0; j < 4; ++j)
          acc[i][j] =
              __builtin_amdgcn_mfma_f32_16x16x32_bf16(av[s][i], bv[s][j], acc[i][j], 0, 0, 0);
    __builtin_amdgcn_s_setprio(0);
    if (c + 1 < NT) {
      __syncthreads();  // WAR: all lgkm reads retired (consumed by MFMA) before restage
      __builtin_amdgcn_sched_barrier(0);
    }
  }

  // epilogue (overlaps co-resident blocks' main loops)
#pragma unroll
  for (int i = 0; i < 4; ++i)
#pragma unroll
    for (int j = 0; j < 4; ++j) {
      const int cg = n0 + wn + j * 16 + fr;
      const float bb = bias[cg];
#pragma unroll
      for (int r = 0; r < 4; ++r) {
        const int rg = m0 + wm + i * 16 + fq * 4 + r;
        if (EPI == 0) {
          gout[(size_t)rg * NALL + cg] = f2bf(gelu_fast(acc[i][j][r] + bb));
        } else {
          const size_t off = (size_t)rg * NALL + cg;
          out[off] = out[off] + acc[i][j][r] + bb;
        }
      }
    }
}

extern "C" void kernel_launch(void* const* d_in, const int* in_sizes, int n_in, void* d_out,
                              int out_size, void* d_ws, size_t ws_size, hipStream_t stream) {
  const float* x = (const float*)d_in[0];
  const float* logA = (const float*)d_in[1];
  const float* Bm = (const float*)d_in[2];
  const float* Cm = (const float*)d_in[3];
  const float* Dv = (const float*)d_in[4];
  const float* logdt = (const float*)d_in[5];
  const float* gamma = (const float*)d_in[6];
  const float* beta = (const float*)d_in[7];
  const float* W1 = (const float*)d_in[8];
  const float* b1 = (const float*)d_in[9];
  const float* W2 = (const float*)d_in[10];
  const float* b2 = (const float*)d_in[11];
  float* out = (float*)d_out;

  // workspace layout (bytes). xbf aliases the (later) g region.
  char* ws = (char*)d_ws;
  float* mu1 = (float*)(ws + 0);
  float* rstd1 = (float*)(ws + 131072);
  float* ends = (float*)(ws + 262144);
  float* gB = (float*)(ws + 524288);
  float* bB = (float*)(ws + 524800);
  unsigned short* Bgt = (unsigned short*)(ws + 525312);   // 64 KB [64][512]
  unsigned short* ctb = (unsigned short*)(ws + 590848);   // 64 KB [512][64]
  unsigned short* w1t = (unsigned short*)(ws + 656384);   // 1 MB  [1024][512]
  unsigned short* w2t = (unsigned short*)(ws + 1704960);  // 1 MB  [512][1024]
  unsigned short* g = (unsigned short*)(ws + 2753536);    // 64 MB [32768][1024]
  unsigned short* xbf = (unsigned short*)(ws + 2753536);  // 32 MB (dead before g written)
  float* xB = (float*)(ws + 69862400);                    // 8 MB [M][64]
  unsigned short* hsb = (unsigned short*)(ws + 78251008); // 4 MB bf16 [M][64]
  unsigned short* yn = (unsigned short*)(ws + 82445312);  // 32 MB bf16

  prep_all_kernel<<<280, 256, 0, stream>>>(W1, W2, Cm, Bm, gamma, beta, w1t, w2t, ctb, Bgt, gB,
                                           bB);
  ln_stats_kernel<<<MROWS / 4, 256, 0, stream>>>(x, mu1, rstd1, xbf);
  xb_mfma_kernel<<<MROWS / 128, 256, 0, stream>>>(xbf, Bgt, mu1, rstd1, gB, bB, xB);
  scan_ends_kernel<<<256, 128, 0, stream>>>(xB, logA, logdt, ends);
  scan_fix_kernel<<<256, 128, 0, stream>>>(logA, logdt, ends, xB, hsb);
  y_ln_fused_kernel<<<MROWS / 128, 512, 0, stream>>>(hsb, ctb, x, mu1, rstd1, gamma, beta, Dv,
                                                     out, yn);
  gemm128_kernel<512, 1024, 0><<<dim3(1024 / 128, MROWS / 128), 256, 0, stream>>>(
      yn, w1t, b1, g, nullptr);
  gemm128_kernel<1024, 512, 1><<<dim3(512 / 128, MROWS / 128), 256, 0, stream>>>(
      g, w2t, b2, nullptr, out);
}

// Round 6
// 355.456 us; speedup vs baseline: 1.0238x; 1.0238x over previous
//
#include <hip/hip_runtime.h>
#include <math.h>

#define BATCH 8
#define SEQL 4096
#define DMODEL 512
#define SDIM 64
#define MROWS (BATCH * SEQL)  // 32768
#define LN_EPS 1e-5f

typedef __attribute__((ext_vector_type(8))) short bf16x8;
typedef __attribute__((ext_vector_type(4))) float f32x4;

// ---------- helpers ----------
__device__ __forceinline__ float wave_sum(float v) {
#pragma unroll
  for (int off = 32; off > 0; off >>= 1) v += __shfl_xor(v, off, 64);
  return v;
}

__device__ __forceinline__ unsigned short f2bf(float f) {  // RNE float->bf16
  unsigned int u = __float_as_uint(f);
  u += 0x7fffu + ((u >> 16) & 1u);
  return (unsigned short)(u >> 16);
}

__device__ __forceinline__ float frcp(float x) {  // fast v_rcp (~1e-6 rel err, 1 inst)
  float r;
  asm("v_rcp_f32 %0, %1" : "=v"(r) : "v"(x));
  return r;
}

// fast erf-based gelu (A&S 7.1.26); frcp replaces precise-div (was ~13 insts)
__device__ __forceinline__ float gelu_fast(float v) {
  float s = v * 0.70710678118654752f;
  float ax = fabsf(s);
  float t = frcp(1.0f + 0.3275911f * ax);
  float p = ((((1.061405429f * t - 1.453152027f) * t + 1.421413741f) * t - 0.284496736f) * t +
             0.254829592f) *
            t;
  float er = 1.0f - p * __expf(-ax * ax);
  er = copysignf(er, s);
  return 0.5f * v * (1.0f + er);
}

__device__ __forceinline__ void gl2lds16(const void* g, void* l) {
  // async global->LDS, 16B/lane; LDS dest = wave-uniform base + lane*16
  __builtin_amdgcn_global_load_lds((const __attribute__((address_space(1))) void*)g,
                                   (__attribute__((address_space(3))) void*)l, 16, 0, 0);
}

// ---------- prep: all weight transposes + B-prep in ONE kernel ----------
__device__ __forceinline__ void transpose_body(const float* __restrict__ W,
                                               unsigned short* __restrict__ Wt, int K, int N,
                                               int bx, int by,
                                               unsigned short (*tile)[65]) {
  int k0 = by * 64, n0 = bx * 64;
  int tx = threadIdx.x & 15, ty = threadIdx.x >> 4;
#pragma unroll
  for (int p = 0; p < 4; ++p) {
    int k = p * 16 + ty;
    float4 v = *(const float4*)&W[(size_t)(k0 + k) * N + n0 + tx * 4];
    tile[tx * 4 + 0][k] = f2bf(v.x);
    tile[tx * 4 + 1][k] = f2bf(v.y);
    tile[tx * 4 + 2][k] = f2bf(v.z);
    tile[tx * 4 + 3][k] = f2bf(v.w);
  }
  __syncthreads();
#pragma unroll
  for (int p = 0; p < 4; ++p) {
    int n = p * 16 + ty;
    ushort4 o;
    o.x = tile[n][tx * 4 + 0];
    o.y = tile[n][tx * 4 + 1];
    o.z = tile[n][tx * 4 + 2];
    o.w = tile[n][tx * 4 + 3];
    *(ushort4*)&Wt[(size_t)(n0 + n) * K + k0 + tx * 4] = o;
  }
}

__global__ __launch_bounds__(256) void prep_all_kernel(
    const float* __restrict__ W1, const float* __restrict__ W2, const float* __restrict__ Cm,
    const float* __restrict__ Bm, const float* __restrict__ gamma,
    const float* __restrict__ beta, unsigned short* __restrict__ w1t,
    unsigned short* __restrict__ w2t, unsigned short* __restrict__ ctb,
    unsigned short* __restrict__ Bgt, float* __restrict__ gB, float* __restrict__ bB) {
  __shared__ unsigned short tile[64][65];
  int b = blockIdx.x;
  if (b < 128) {  // W1 [512][1024] -> w1t [1024][512]
    transpose_body(W1, w1t, 512, 1024, b & 15, b >> 4, tile);
  } else if (b < 256) {  // W2 [1024][512] -> w2t [512][1024]
    transpose_body(W2, w2t, 1024, 512, (b - 128) & 7, (b - 128) >> 3, tile);
  } else if (b < 264) {  // Cm [64][512] -> ctb [512][64]
    transpose_body(Cm, ctb, 64, 512, b - 256, 0, tile);
  } else {  // Bgt[s][d]=bf16(gamma[d]*B[d][s]); gB[s]=gamma@B; bB[s]=beta@B
    int s = (b - 264) * 4 + (threadIdx.x >> 6);
    int l = threadIdx.x & 63;
    float gs = 0.0f, bs = 0.0f;
    unsigned short tmp[8];
#pragma unroll
    for (int u = 0; u < 8; ++u) {
      int d = l * 8 + u;
      float bv = Bm[(size_t)d * SDIM + s];
      float gv = gamma[d], ev = beta[d];
      gs += gv * bv;
      bs += ev * bv;
      tmp[u] = f2bf(gv * bv);
    }
    *(ushort4*)&Bgt[(size_t)s * DMODEL + l * 8] = make_ushort4(tmp[0], tmp[1], tmp[2], tmp[3]);
    *(ushort4*)&Bgt[(size_t)s * DMODEL + l * 8 + 4] =
        make_ushort4(tmp[4], tmp[5], tmp[6], tmp[7]);
    gs = wave_sum(gs);
    bs = wave_sum(bs);
    if (l == 0) {
      gB[s] = gs;
      bB[s] = bs;
    }
  }
}

// ---------- K1+K2 fused: LN stats + xB = rstd*(x@Bgt) - rstd*mu*gB + bB ----------
// 64 rows/block, 256 thr (4 waves x 16 rows). x read ONCE (fp32), cast to bf16 in
// swizzled LDS; B-frags read from L2-hot Bgt (64 KB, broadcast). 2 blocks/CU.
__global__ __launch_bounds__(256, 2) void lnxb_kernel(
    const float* __restrict__ x, const unsigned short* __restrict__ Bgt,
    const float* __restrict__ gB, const float* __restrict__ bB, float* __restrict__ mu1,
    float* __restrict__ rstd1, float* __restrict__ xB) {
  __shared__ alignas(16) unsigned short As[64 * 512];  // 64 KB, swizzled 16B slots
  __shared__ float mu_s[64], rs_s[64];
  const int t = threadIdx.x;
  const int m0 = blockIdx.x * 64;
  const int row = t >> 2, q = t & 3;  // 4 threads per row, 128 cols each
  const float4* xp = (const float4*)(x + (size_t)(m0 + row) * DMODEL + q * 128);
  float s1 = 0.0f, s2 = 0.0f;
#pragma unroll
  for (int u = 0; u < 16; ++u) {
    float4 va = xp[2 * u], vb = xp[2 * u + 1];
    s1 += va.x + va.y + va.z + va.w + vb.x + vb.y + vb.z + vb.w;
    s2 += va.x * va.x + va.y * va.y + va.z * va.z + va.w * va.w + vb.x * vb.x + vb.y * vb.y +
          vb.z * vb.z + vb.w * vb.w;
    const int slot = q * 16 + u;
    const int sw = (slot & ~7) | ((slot ^ row) & 7);
    uint4 pk;
    pk.x = (unsigned)f2bf(va.x) | ((unsigned)f2bf(va.y) << 16);
    pk.y = (unsigned)f2bf(va.z) | ((unsigned)f2bf(va.w) << 16);
    pk.z = (unsigned)f2bf(vb.x) | ((unsigned)f2bf(vb.y) << 16);
    pk.w = (unsigned)f2bf(vb.z) | ((unsigned)f2bf(vb.w) << 16);
    *(uint4*)&As[(size_t)row * 512 + sw * 8] = pk;
  }
  // reduce the 4 q-threads of each row (lanes row*4+q within wave)
  s1 += __shfl_xor(s1, 1, 64);
  s1 += __shfl_xor(s1, 2, 64);
  s2 += __shfl_xor(s2, 1, 64);
  s2 += __shfl_xor(s2, 2, 64);
  if (q == 0) {
    float m = s1 * (1.0f / DMODEL);
    float var = s2 * (1.0f / DMODEL) - m * m;
    float rs = rsqrtf(var + LN_EPS);
    mu_s[row] = m;
    rs_s[row] = rs;
    mu1[m0 + row] = m;
    rstd1[m0 + row] = rs;
  }
  __syncthreads();
  // MFMA: wave w -> rows wm..wm+15, all 64 s-cols, K=512
  const int wid = t >> 6, lane = t & 63;
  const int wm = wid * 16;
  const int fr = lane & 15, fq = lane >> 4;
  const int arow = wm + fr;
  f32x4 acc[4] = {};
#pragma unroll
  for (int kk = 0; kk < 16; ++kk) {
    const int slot = kk * 4 + fq;
    const int sw = (slot & ~7) | ((slot ^ arow) & 7);
    bf16x8 a = *(const bf16x8*)&As[(size_t)arow * 512 + sw * 8];
#pragma unroll
    for (int j = 0; j < 4; ++j) {
      bf16x8 b = *(const bf16x8*)&Bgt[(size_t)(j * 16 + fr) * DMODEL + kk * 32 + fq * 8];
      acc[j] = __builtin_amdgcn_mfma_f32_16x16x32_bf16(a, b, acc[j], 0, 0, 0);
    }
  }
#pragma unroll
  for (int j = 0; j < 4; ++j) {
    const int s = j * 16 + fr;
    const float gs = gB[s], bs = bB[s];
#pragma unroll
    for (int r = 0; r < 4; ++r) {
      const int ml = wm + fq * 4 + r;
      xB[(size_t)(m0 + ml) * SDIM + s] = rs_s[ml] * acc[j][r] - mu_s[ml] * rs_s[ml] * gs + bs;
    }
  }
}

// ---------- K3a/b: exact chunked scan h_t = a*h_{t-1} + x_t over L ----------
__global__ void scan_ends_kernel(const float* __restrict__ xB, const float* __restrict__ logA,
                                 const float* __restrict__ logdt, float* __restrict__ ends) {
  int t = blockIdx.x * 128 + threadIdx.x;
  int s = t & 63;
  int c = (t >> 6) & 63;
  int b = t >> 12;
  float a = expf(-expf(logA[s]) * expf(logdt[0]));
  const float* p = xB + ((size_t)(b * SEQL + c * 64)) * SDIM + s;
  float e = 0.0f;
#pragma unroll
  for (int i = 0; i < 64; ++i) e = a * e + p[(size_t)i * SDIM];
  ends[(b * 64 + c) * 64 + s] = e;
}

// carry inlined: each wave (uniform c) recomputes its chunk-entry state from ends (L2-hot)
__global__ void scan_fix_kernel(const float* __restrict__ logA, const float* __restrict__ logdt,
                                const float* __restrict__ ends, const float* __restrict__ xB,
                                unsigned short* __restrict__ hsb) {
  int t = blockIdx.x * 128 + threadIdx.x;
  int s = t & 63;
  int c = (t >> 6) & 63;
  int b = t >> 12;
  float a = expf(-expf(logA[s]) * expf(logdt[0]));
  float a64 = a;
#pragma unroll
  for (int i = 0; i < 6; ++i) a64 *= a64;  // a^64
  float h = 0.0f;
  for (int cp = 0; cp < c; ++cp) h = a64 * h + ends[(b * 64 + cp) * 64 + s];
  const float* p = xB + ((size_t)(b * SEQL + c * 64)) * SDIM + s;
  unsigned short* q = hsb + ((size_t)(b * SEQL + c * 64)) * SDIM + s;
#pragma unroll
  for (int i = 0; i < 64; ++i) {
    h = a * h + p[(size_t)i * SDIM];
    q[(size_t)i * SDIM] = f2bf(h);
  }
}

// ---------- K4: y = hsb@ctb^T + xn*D + x -> out ; LN(y) -> yn (wave-private) ----------
// 64 rows/block, 256 thr, 4 waves x (16 rows x FULL 512 cols). LN reduce = shfl only
// (no LDS atomics, 1 barrier). LDS = Bs 64 KB -> 2 blocks/CU, grid 512 = 2/CU.
__global__ __launch_bounds__(256, 2) void y_ln_fused_kernel(
    const unsigned short* __restrict__ hsb, const unsigned short* __restrict__ ctb,
    const float* __restrict__ x, const float* __restrict__ mu1,
    const float* __restrict__ rstd1, const float* __restrict__ gamma,
    const float* __restrict__ beta, const float* __restrict__ Dv, float* __restrict__ out,
    unsigned short* __restrict__ yn) {
  __shared__ alignas(16) unsigned short Bs[512 * 64];  // 64 KB, swizzled
  const int t = threadIdx.x;
  const int wid = t >> 6, lane = t & 63;
  const int m0 = blockIdx.x * 64;
  const int wm = wid * 16;
  const int fr = lane & 15, fq = lane >> 4;
  const int srow = t >> 3;                          // 0..31
  const int ksw = ((t & 7) ^ ((t >> 3) & 7)) << 3;  // pre-swizzled src k-offset
#pragma unroll
  for (int h = 0; h < 16; ++h)
    gl2lds16(ctb + (size_t)(h * 32 + srow) * 64 + ksw, &Bs[(h * 32 + wid * 8) * 64]);
  asm volatile("s_waitcnt vmcnt(0)" ::: "memory");
  __builtin_amdgcn_s_barrier();

  // A-frags (K=64) straight from global (hsb read exactly once per row)
  bf16x8 a0 = *(const bf16x8*)&hsb[(size_t)(m0 + wm + fr) * 64 + fq * 8];
  bf16x8 a1 = *(const bf16x8*)&hsb[(size_t)(m0 + wm + fr) * 64 + 32 + fq * 8];
  f32x4 acc[32];
#pragma unroll
  for (int j = 0; j < 32; ++j) acc[j] = f32x4{0.f, 0.f, 0.f, 0.f};
#pragma unroll
  for (int j = 0; j < 32; ++j) {
    bf16x8 b0 = *(const bf16x8*)&Bs[(j * 16 + fr) * 64 + ((fq) ^ (fr & 7)) * 8];
    bf16x8 b1 = *(const bf16x8*)&Bs[(j * 16 + fr) * 64 + ((4 + fq) ^ (fr & 7)) * 8];
    acc[j] = __builtin_amdgcn_mfma_f32_16x16x32_bf16(a0, b0, acc[j], 0, 0, 0);
    acc[j] = __builtin_amdgcn_mfma_f32_16x16x32_bf16(a1, b1, acc[j], 0, 0, 0);
  }

  float mur[4], rsr[4];
#pragma unroll
  for (int r = 0; r < 4; ++r) {
    const int m = m0 + wm + fq * 4 + r;
    mur[r] = mu1[m];
    rsr[r] = rstd1[m];
  }
  float s1[4] = {0.f, 0.f, 0.f, 0.f}, s2[4] = {0.f, 0.f, 0.f, 0.f};
#pragma unroll
  for (int j = 0; j < 32; ++j) {
    const int cg = j * 16 + fr;
    const float ga = gamma[cg], be = beta[cg], dd = Dv[cg];
#pragma unroll
    for (int r = 0; r < 4; ++r) {
      const int m = m0 + wm + fq * 4 + r;
      const float xv = x[(size_t)m * DMODEL + cg];
      float yv = acc[j][r] + ((xv - mur[r]) * rsr[r] * ga + be) * dd + xv;
      out[(size_t)m * DMODEL + cg] = yv;
      acc[j][r] = yv;
      s1[r] += yv;
      s2[r] += yv * yv;
    }
  }
#pragma unroll
  for (int r = 0; r < 4; ++r) {
#pragma unroll
    for (int off = 1; off < 16; off <<= 1) {
      s1[r] += __shfl_xor(s1[r], off, 64);
      s2[r] += __shfl_xor(s2[r], off, 64);
    }
  }
  float mu2[4], rs2[4];
#pragma unroll
  for (int r = 0; r < 4; ++r) {
    mu2[r] = s1[r] * (1.0f / DMODEL);
    rs2[r] = rsqrtf(s2[r] * (1.0f / DMODEL) - mu2[r] * mu2[r] + LN_EPS);
  }
#pragma unroll
  for (int j = 0; j < 32; ++j) {
    const int cg = j * 16 + fr;
    const float ga = gamma[cg], be = beta[cg];
#pragma unroll
    for (int r = 0; r < 4; ++r) {
      const int m = m0 + wm + fq * 4 + r;
      yn[(size_t)m * DMODEL + cg] = f2bf((acc[j][r] - mu2[r]) * rs2[r] * ga + be);
    }
  }
}

// ---------- 128x128-tile, BK=64, 4-wave, double-buffered, 2 blocks/CU GEMM ----------
// (R4 config: best measured MLP GEMM; R5's single-buffer 4/CU regressed via L2 thrash.)
template <int K, int NALL, int EPI>
__global__ __launch_bounds__(256, 2) void gemm128_kernel(
    const unsigned short* __restrict__ Am, const unsigned short* __restrict__ Bm,
    const float* __restrict__ bias, unsigned short* __restrict__ gout,
    float* __restrict__ out) {
  __shared__ alignas(16) unsigned short As[2][128 * 64];  // 32 KB
  __shared__ alignas(16) unsigned short Bs[2][128 * 64];  // 32 KB
  const int t = threadIdx.x;
  const int wid = t >> 6, lane = t & 63;
  // bijective XCD-aware swizzle (nwg % 8 == 0 for both launches)
  const int nwg = gridDim.x * gridDim.y;
  const int orig = blockIdx.y * gridDim.x + blockIdx.x;
  const int swz = (orig & 7) * (nwg >> 3) + (orig >> 3);
  const int m0 = (swz / gridDim.x) * 128, n0 = (swz % gridDim.x) * 128;
  const int wm = (wid >> 1) * 64, wn = (wid & 1) * 64;
  const int fr = lane & 15, fq = lane >> 4;
  constexpr int NT = K / 64;
  const int srow = t >> 3;                          // 0..31
  const int ksw = ((t & 7) ^ ((t >> 3) & 7)) << 3;  // pre-swizzled src k-offset (elems)

  auto stageA = [&](int bb, int kt) {
    const unsigned short* s0 = Am + (size_t)(m0 + srow) * K + kt * 64 + ksw;
#pragma unroll
    for (int q = 0; q < 4; ++q)
      gl2lds16(s0 + (size_t)(q * 32) * K, &As[bb][(q * 32 + wid * 8) * 64]);
  };
  auto stageB = [&](int bb, int kt) {
    const unsigned short* s0 = Bm + (size_t)(n0 + srow) * K + kt * 64 + ksw;
#pragma unroll
    for (int q = 0; q < 4; ++q)
      gl2lds16(s0 + (size_t)(q * 32) * K, &Bs[bb][(q * 32 + wid * 8) * 64]);
  };

  // prologue: stage tile0 -> buf0
  stageA(0, 0);
  stageB(0, 0);
  asm volatile("s_waitcnt vmcnt(0)" ::: "memory");
  __builtin_amdgcn_s_barrier();
  __builtin_amdgcn_sched_barrier(0);

  f32x4 acc[4][4] = {};
  for (int c = 0; c < NT; ++c) {
    const int b = c & 1;
    if (c + 1 < NT) {  // issue next-tile staging first
      stageA(b ^ 1, c + 1);
      stageB(b ^ 1, c + 1);
    }
    bf16x8 av[2][4], bv[2][4];
#pragma unroll
    for (int s = 0; s < 2; ++s) {
#pragma unroll
      for (int i = 0; i < 4; ++i)
        av[s][i] =
            *(const bf16x8*)&As[b][(wm + i * 16 + fr) * 64 + ((s * 4 + fq) ^ (fr & 7)) * 8];
#pragma unroll
      for (int j = 0; j < 4; ++j)
        bv[s][j] =
            *(const bf16x8*)&Bs[b][(wn + j * 16 + fr) * 64 + ((s * 4 + fq) ^ (fr & 7)) * 8];
    }
    __builtin_amdgcn_s_setprio(1);
#pragma unroll
    for (int s = 0; s < 2; ++s)
#pragma unroll
      for (int i = 0; i < 4; ++i)
#pragma unroll
        for (int j = 0; j < 4; ++j)
          acc[i][j] =
              __builtin_amdgcn_mfma_f32_16x16x32_bf16(av[s][i], bv[s][j], acc[i][j], 0, 0, 0);
    __builtin_amdgcn_s_setprio(0);
    if (c + 1 < NT) {
      asm volatile("s_waitcnt vmcnt(0)" ::: "memory");  // next tile landed
      __builtin_amdgcn_s_barrier();
      __builtin_amdgcn_sched_barrier(0);  // keep next iter's reads below the barrier
    }
  }

  // epilogue (overlaps the co-resident block's main loop)
#pragma unroll
  for (int i = 0; i < 4; ++i)
#pragma unroll
    for (int j = 0; j < 4; ++j) {
      const int cg = n0 + wn + j * 16 + fr;
      const float bb = bias[cg];
#pragma unroll
      for (int r = 0; r < 4; ++r) {
        const int rg = m0 + wm + i * 16 + fq * 4 + r;
        if (EPI == 0) {
          gout[(size_t)rg * NALL + cg] = f2bf(gelu_fast(acc[i][j][r] + bb));
        } else {
          const size_t off = (size_t)rg * NALL + cg;
          out[off] = out[off] + acc[i][j][r] + bb;
        }
      }
    }
}

extern "C" void kernel_launch(void* const* d_in, const int* in_sizes, int n_in, void* d_out,
                              int out_size, void* d_ws, size_t ws_size, hipStream_t stream) {
  const float* x = (const float*)d_in[0];
  const float* logA = (const float*)d_in[1];
  const float* Bm = (const float*)d_in[2];
  const float* Cm = (const float*)d_in[3];
  const float* Dv = (const float*)d_in[4];
  const float* logdt = (const float*)d_in[5];
  const float* gamma = (const float*)d_in[6];
  const float* beta = (const float*)d_in[7];
  const float* W1 = (const float*)d_in[8];
  const float* b1 = (const float*)d_in[9];
  const float* W2 = (const float*)d_in[10];
  const float* b2 = (const float*)d_in[11];
  float* out = (float*)d_out;

  // workspace layout (bytes)
  char* ws = (char*)d_ws;
  float* mu1 = (float*)(ws + 0);
  float* rstd1 = (float*)(ws + 131072);
  float* ends = (float*)(ws + 262144);
  float* gB = (float*)(ws + 524288);
  float* bB = (float*)(ws + 524800);
  unsigned short* Bgt = (unsigned short*)(ws + 525312);   // 64 KB [64][512]
  unsigned short* ctb = (unsigned short*)(ws + 590848);   // 64 KB [512][64]
  unsigned short* w1t = (unsigned short*)(ws + 656384);   // 1 MB  [1024][512]
  unsigned short* w2t = (unsigned short*)(ws + 1704960);  // 1 MB  [512][1024]
  unsigned short* g = (unsigned short*)(ws + 2753536);    // 64 MB [32768][1024]
  float* xB = (float*)(ws + 69862400);                    // 8 MB [M][64]
  unsigned short* hsb = (unsigned short*)(ws + 78251008); // 4 MB bf16 [M][64]
  unsigned short* yn = (unsigned short*)(ws + 82445312);  // 32 MB bf16

  prep_all_kernel<<<280, 256, 0, stream>>>(W1, W2, Cm, Bm, gamma, beta, w1t, w2t, ctb, Bgt, gB,
                                           bB);
  lnxb_kernel<<<MROWS / 64, 256, 0, stream>>>(x, Bgt, gB, bB, mu1, rstd1, xB);
  scan_ends_kernel<<<256, 128, 0, stream>>>(xB, logA, logdt, ends);
  scan_fix_kernel<<<256, 128, 0, stream>>>(logA, logdt, ends, xB, hsb);
  y_ln_fused_kernel<<<MROWS / 64, 256, 0, stream>>>(hsb, ctb, x, mu1, rstd1, gamma, beta, Dv,
                                                    out, yn);
  gemm128_kernel<512, 1024, 0><<<dim3(1024 / 128, MROWS / 128), 256, 0, stream>>>(
      yn, w1t, b1, g, nullptr);
  gemm128_kernel<1024, 512, 1><<<dim3(512 / 128, MROWS / 128), 256, 0, stream>>>(
      g, w2t, b2, nullptr, out);
}

// Round 7
// 354.193 us; speedup vs baseline: 1.0274x; 1.0036x over previous
//
#include <hip/hip_runtime.h>
#include <math.h>

#define BATCH 8
#define SEQL 4096
#define DMODEL 512
#define SDIM 64
#define MROWS (BATCH * SEQL)  // 32768
#define LN_EPS 1e-5f

typedef __attribute__((ext_vector_type(8))) short bf16x8;
typedef __attribute__((ext_vector_type(4))) float f32x4;

// ---------- helpers ----------
__device__ __forceinline__ float wave_sum(float v) {
#pragma unroll
  for (int off = 32; off > 0; off >>= 1) v += __shfl_xor(v, off, 64);
  return v;
}

__device__ __forceinline__ unsigned short f2bf(float f) {  // RNE float->bf16
  unsigned int u = __float_as_uint(f);
  u += 0x7fffu + ((u >> 16) & 1u);
  return (unsigned short)(u >> 16);
}

__device__ __forceinline__ float frcp(float x) {  // fast v_rcp (~1e-6 rel err, 1 inst)
  float r;
  asm("v_rcp_f32 %0, %1" : "=v"(r) : "v"(x));
  return r;
}

// fast erf-based gelu (A&S 7.1.26); frcp replaces precise-div (~13 insts -> 1)
__device__ __forceinline__ float gelu_fast(float v) {
  float s = v * 0.70710678118654752f;
  float ax = fabsf(s);
  float t = frcp(1.0f + 0.3275911f * ax);
  float p = ((((1.061405429f * t - 1.453152027f) * t + 1.421413741f) * t - 0.284496736f) * t +
             0.254829592f) *
            t;
  float er = 1.0f - p * __expf(-ax * ax);
  er = copysignf(er, s);
  return 0.5f * v * (1.0f + er);
}

__device__ __forceinline__ void gl2lds16(const void* g, void* l) {
  // async global->LDS, 16B/lane; LDS dest = wave-uniform base + lane*16
  __builtin_amdgcn_global_load_lds((const __attribute__((address_space(1))) void*)g,
                                   (__attribute__((address_space(3))) void*)l, 16, 0, 0);
}

// ---------- K1: LN1 stats for x (mu, rstd per row) + bf16 cast of x ----------
__global__ void ln_stats_kernel(const float* __restrict__ x, float* __restrict__ mu,
                                float* __restrict__ rstd, unsigned short* __restrict__ xbf) {
  int row = blockIdx.x * 4 + (threadIdx.x >> 6);
  int lane = threadIdx.x & 63;
  const float4* xp = (const float4*)(x + (size_t)row * DMODEL);
  float4 a = xp[lane * 2];
  float4 b = xp[lane * 2 + 1];
  float s = a.x + a.y + a.z + a.w + b.x + b.y + b.z + b.w;
  float q = a.x * a.x + a.y * a.y + a.z * a.z + a.w * a.w + b.x * b.x + b.y * b.y +
            b.z * b.z + b.w * b.w;
  s = wave_sum(s);
  q = wave_sum(q);
  uint4 pk;
  pk.x = (unsigned)f2bf(a.x) | ((unsigned)f2bf(a.y) << 16);
  pk.y = (unsigned)f2bf(a.z) | ((unsigned)f2bf(a.w) << 16);
  pk.z = (unsigned)f2bf(b.x) | ((unsigned)f2bf(b.y) << 16);
  pk.w = (unsigned)f2bf(b.z) | ((unsigned)f2bf(b.w) << 16);
  ((uint4*)(xbf + (size_t)row * DMODEL))[lane] = pk;
  if (lane == 0) {
    float m = s * (1.0f / DMODEL);
    float var = q * (1.0f / DMODEL) - m * m;
    mu[row] = m;
    rstd[row] = rsqrtf(var + LN_EPS);
  }
}

// ---------- prep: all weight transposes + B-prep in ONE kernel ----------
__device__ __forceinline__ void transpose_body(const float* __restrict__ W,
                                               unsigned short* __restrict__ Wt, int K, int N,
                                               int bx, int by,
                                               unsigned short (*tile)[65]) {
  int k0 = by * 64, n0 = bx * 64;
  int tx = threadIdx.x & 15, ty = threadIdx.x >> 4;
#pragma unroll
  for (int p = 0; p < 4; ++p) {
    int k = p * 16 + ty;
    float4 v = *(const float4*)&W[(size_t)(k0 + k) * N + n0 + tx * 4];
    tile[tx * 4 + 0][k] = f2bf(v.x);
    tile[tx * 4 + 1][k] = f2bf(v.y);
    tile[tx * 4 + 2][k] = f2bf(v.z);
    tile[tx * 4 + 3][k] = f2bf(v.w);
  }
  __syncthreads();
#pragma unroll
  for (int p = 0; p < 4; ++p) {
    int n = p * 16 + ty;
    ushort4 o;
    o.x = tile[n][tx * 4 + 0];
    o.y = tile[n][tx * 4 + 1];
    o.z = tile[n][tx * 4 + 2];
    o.w = tile[n][tx * 4 + 3];
    *(ushort4*)&Wt[(size_t)(n0 + n) * K + k0 + tx * 4] = o;
  }
}

__global__ __launch_bounds__(256) void prep_all_kernel(
    const float* __restrict__ W1, const float* __restrict__ W2, const float* __restrict__ Cm,
    const float* __restrict__ Bm, const float* __restrict__ gamma,
    const float* __restrict__ beta, unsigned short* __restrict__ w1t,
    unsigned short* __restrict__ w2t, unsigned short* __restrict__ ctb,
    unsigned short* __restrict__ Bgt, float* __restrict__ gB, float* __restrict__ bB) {
  __shared__ unsigned short tile[64][65];
  int b = blockIdx.x;
  if (b < 128) {  // W1 [512][1024] -> w1t [1024][512]
    transpose_body(W1, w1t, 512, 1024, b & 15, b >> 4, tile);
  } else if (b < 256) {  // W2 [1024][512] -> w2t [512][1024]
    transpose_body(W2, w2t, 1024, 512, (b - 128) & 7, (b - 128) >> 3, tile);
  } else if (b < 264) {  // Cm [64][512] -> ctb [512][64]
    transpose_body(Cm, ctb, 64, 512, b - 256, 0, tile);
  } else {  // Bgt[s][d]=bf16(gamma[d]*B[d][s]); gB[s]=gamma@B; bB[s]=beta@B
    int s = (b - 264) * 4 + (threadIdx.x >> 6);
    int l = threadIdx.x & 63;
    float gs = 0.0f, bs = 0.0f;
    unsigned short tmp[8];
#pragma unroll
    for (int u = 0; u < 8; ++u) {
      int d = l * 8 + u;
      float bv = Bm[(size_t)d * SDIM + s];
      float gv = gamma[d], ev = beta[d];
      gs += gv * bv;
      bs += ev * bv;
      tmp[u] = f2bf(gv * bv);
    }
    *(ushort4*)&Bgt[(size_t)s * DMODEL + l * 8] = make_ushort4(tmp[0], tmp[1], tmp[2], tmp[3]);
    *(ushort4*)&Bgt[(size_t)s * DMODEL + l * 8 + 4] =
        make_ushort4(tmp[4], tmp[5], tmp[6], tmp[7]);
    gs = wave_sum(gs);
    bs = wave_sum(bs);
    if (l == 0) {
      gB[s] = gs;
      bB[s] = bs;
    }
  }
}

// ---------- K2: xB = rstd*(xbf@Bgt) - rstd*mu*gB + bB   (MFMA bf16) ----------
__global__ __launch_bounds__(256) void xb_mfma_kernel(
    const unsigned short* __restrict__ xbf, const unsigned short* __restrict__ Bgt,
    const float* __restrict__ mu, const float* __restrict__ rstd, const float* __restrict__ gB,
    const float* __restrict__ bB, float* __restrict__ xB) {
  __shared__ unsigned short As[128 * 32];  // [m][k]
  __shared__ unsigned short Bs[64 * 32];   // [s][k]
  const int t = threadIdx.x;
  const int wave = t >> 6, lane = t & 63;
  const int m0 = blockIdx.x * 128;
  const int wm = wave * 32;
  const int row = t >> 2, seg = t & 3;
  const int fr = lane & 15, fq = lane >> 4;
  f32x4 acc[2][4] = {};
  for (int k0 = 0; k0 < DMODEL; k0 += 32) {
    __syncthreads();
    gl2lds16(xbf + (size_t)(m0 + row) * DMODEL + k0 + seg * 8, As + (size_t)(wave * 16) * 32);
    gl2lds16(xbf + (size_t)(m0 + 64 + row) * DMODEL + k0 + seg * 8,
             As + (size_t)(64 + wave * 16) * 32);
    gl2lds16(Bgt + (size_t)row * DMODEL + k0 + seg * 8, Bs + (size_t)(wave * 16) * 32);
    __syncthreads();
#pragma unroll
    for (int i = 0; i < 2; ++i) {
      bf16x8 a = *(const bf16x8*)&As[(wm + i * 16 + fr) * 32 + fq * 8];
#pragma unroll
      for (int j = 0; j < 4; ++j) {
        bf16x8 b = *(const bf16x8*)&Bs[(j * 16 + fr) * 32 + fq * 8];
        acc[i][j] = __builtin_amdgcn_mfma_f32_16x16x32_bf16(a, b, acc[i][j], 0, 0, 0);
      }
    }
  }
#pragma unroll
  for (int i = 0; i < 2; ++i)
#pragma unroll
    for (int r = 0; r < 4; ++r) {
      const int m = m0 + wm + i * 16 + fq * 4 + r;
      const float rr = rstd[m], negmurr = -mu[m] * rstd[m];
#pragma unroll
      for (int j = 0; j < 4; ++j) {
        const int s = j * 16 + fr;
        xB[(size_t)m * SDIM + s] = rr * acc[i][j][r] + negmurr * gB[s] + bB[s];
      }
    }
}

// ---------- K3a/b: exact chunked scan, CHUNK=16 (4x threads vs CHUNK=64) ----------
// 131072 threads (2 waves/CU) instead of 32768 (0.5 waves/CU): the dependent-FMA
// chain is latency-bound, so occupancy is the lever. ends: [8][256][64] f32 (512 KB).
__global__ void scan_ends_kernel(const float* __restrict__ xB, const float* __restrict__ logA,
                                 const float* __restrict__ logdt, float* __restrict__ ends) {
  int t = blockIdx.x * 256 + threadIdx.x;
  int s = t & 63;
  int c = (t >> 6) & 255;
  int b = t >> 14;
  float a = expf(-expf(logA[s]) * expf(logdt[0]));
  const float* p = xB + ((size_t)(b * SEQL + c * 16)) * SDIM + s;
  float e = 0.0f;
#pragma unroll
  for (int i = 0; i < 16; ++i) e = a * e + p[(size_t)i * SDIM];
  ends[((size_t)b * 256 + c) * 64 + s] = e;
}

// carry loop: up to 255 L2-hot coalesced loads + FMA (pipelined); then 16 steps.
__global__ void scan_fix_kernel(const float* __restrict__ logA, const float* __restrict__ logdt,
                                const float* __restrict__ ends, const float* __restrict__ xB,
                                unsigned short* __restrict__ hsb) {
  int t = blockIdx.x * 256 + threadIdx.x;
  int s = t & 63;
  int c = (t >> 6) & 255;
  int b = t >> 14;
  float a = expf(-expf(logA[s]) * expf(logdt[0]));
  float a16 = a;
#pragma unroll
  for (int i = 0; i < 4; ++i) a16 *= a16;  // a^16
  float h = 0.0f;
  for (int cp = 0; cp < c; ++cp) h = a16 * h + ends[((size_t)b * 256 + cp) * 64 + s];
  const float* p = xB + ((size_t)(b * SEQL + c * 16)) * SDIM + s;
  unsigned short* q = hsb + ((size_t)(b * SEQL + c * 16)) * SDIM + s;
#pragma unroll
  for (int i = 0; i < 16; ++i) {
    h = a * h + p[(size_t)i * SDIM];
    q[(size_t)i * SDIM] = f2bf(h);
  }
}

// ---------- K4: y = hsb@ctb^T + xn*D + x -> out ; then LN(y) -> yn (fused) ----------
// 128 rows x full 512 cols per block, 8 waves (2m x 4n), per-wave 64x128, K=64 one-shot.
__global__ __launch_bounds__(512, 2) void y_ln_fused_kernel(
    const unsigned short* __restrict__ hsb, const unsigned short* __restrict__ ctb,
    const float* __restrict__ x, const float* __restrict__ mu1,
    const float* __restrict__ rstd1, const float* __restrict__ gamma,
    const float* __restrict__ beta, const float* __restrict__ Dv, float* __restrict__ out,
    unsigned short* __restrict__ yn) {
  __shared__ alignas(16) unsigned short As[128 * 64];  // 16 KB, swizzled
  __shared__ alignas(16) unsigned short Bs[512 * 64];  // 64 KB, swizzled
  __shared__ float rsum[128], rsq[128];
  const int t = threadIdx.x;
  const int wid = t >> 6, lane = t & 63;
  const int m0 = blockIdx.x * 128;
  const int wm = (wid >> 2) * 64;   // 0 / 64
  const int wn = (wid & 3) * 128;   // 0..384
  const int fr = lane & 15, fq = lane >> 4;
  const int srow = t >> 3;
  const int ksw = ((t & 7) ^ ((t >> 3) & 7)) << 3;  // pre-swizzled src k-offset
  gl2lds16(hsb + (size_t)(m0 + srow) * 64 + ksw, &As[(wid * 8) * 64]);
  gl2lds16(hsb + (size_t)(m0 + 64 + srow) * 64 + ksw, &As[(64 + wid * 8) * 64]);
#pragma unroll
  for (int h = 0; h < 8; ++h)
    gl2lds16(ctb + (size_t)(h * 64 + srow) * 64 + ksw, &Bs[(h * 64 + wid * 8) * 64]);
  if (t < 128) {
    rsum[t] = 0.0f;
    rsq[t] = 0.0f;
  }
  asm volatile("s_waitcnt vmcnt(0)" ::: "memory");
  __builtin_amdgcn_s_barrier();

  f32x4 acc[4][8] = {};
#pragma unroll
  for (int s = 0; s < 2; ++s) {
    bf16x8 af[4], bf[8];
#pragma unroll
    for (int i = 0; i < 4; ++i)
      af[i] = *(const bf16x8*)&As[(wm + i * 16 + fr) * 64 + ((s * 4 + fq) ^ (fr & 7)) * 8];
#pragma unroll
    for (int j = 0; j < 8; ++j)
      bf[j] = *(const bf16x8*)&Bs[(wn + j * 16 + fr) * 64 + ((s * 4 + fq) ^ (fr & 7)) * 8];
#pragma unroll
    for (int i = 0; i < 4; ++i)
#pragma unroll
      for (int j = 0; j < 8; ++j)
        acc[i][j] = __builtin_amdgcn_mfma_f32_16x16x32_bf16(af[i], bf[j], acc[i][j], 0, 0, 0);
  }

  float ga[8], be[8], dd[8];
#pragma unroll
  for (int j = 0; j < 8; ++j) {
    const int cg = wn + j * 16 + fr;
    ga[j] = gamma[cg];
    be[j] = beta[cg];
    dd[j] = Dv[cg];
  }
  float ps[4][4], pq[4][4];
#pragma unroll
  for (int i = 0; i < 4; ++i)
#pragma unroll
    for (int r = 0; r < 4; ++r) {
      const int m = m0 + wm + i * 16 + fq * 4 + r;
      const float mu = mu1[m], rs = rstd1[m];
      float s1 = 0.0f, s2 = 0.0f;
#pragma unroll
      for (int j = 0; j < 8; ++j) {
        const int cg = wn + j * 16 + fr;
        const float xv = x[(size_t)m * DMODEL + cg];
        float yv = acc[i][j][r] + ((xv - mu) * rs * ga[j] + be[j]) * dd[j] + xv;
        out[(size_t)m * DMODEL + cg] = yv;
        acc[i][j][r] = yv;
        s1 += yv;
        s2 += yv * yv;
      }
      ps[i][r] = s1;
      pq[i][r] = s2;
    }
#pragma unroll
  for (int i = 0; i < 4; ++i)
#pragma unroll
    for (int r = 0; r < 4; ++r) {
#pragma unroll
      for (int off = 1; off < 16; off <<= 1) {
        ps[i][r] += __shfl_xor(ps[i][r], off, 64);
        pq[i][r] += __shfl_xor(pq[i][r], off, 64);
      }
    }
  if (fr == 0) {
#pragma unroll
    for (int i = 0; i < 4; ++i)
#pragma unroll
      for (int r = 0; r < 4; ++r) {
        atomicAdd(&rsum[wm + i * 16 + fq * 4 + r], ps[i][r]);
        atomicAdd(&rsq[wm + i * 16 + fq * 4 + r], pq[i][r]);
      }
  }
  __syncthreads();
#pragma unroll
  for (int i = 0; i < 4; ++i)
#pragma unroll
    for (int r = 0; r < 4; ++r) {
      const int rl = wm + i * 16 + fq * 4 + r;
      const int m = m0 + rl;
      const float mu2 = rsum[rl] * (1.0f / DMODEL);
      const float var = rsq[rl] * (1.0f / DMODEL) - mu2 * mu2;
      const float rs2 = rsqrtf(var + LN_EPS);
#pragma unroll
      for (int j = 0; j < 8; ++j) {
        const int cg = wn + j * 16 + fr;
        yn[(size_t)m * DMODEL + cg] = f2bf((acc[i][j][r] - mu2) * rs2 * ga[j] + be[j]);
      }
    }
}

// ---------- 128x128-tile, BK=64, 4-wave, double-buffered, 2 blocks/CU GEMM ----------
// (R4 config: best measured MLP GEMM.)
template <int K, int NALL, int EPI>
__global__ __launch_bounds__(256, 2) void gemm128_kernel(
    const unsigned short* __restrict__ Am, const unsigned short* __restrict__ Bm,
    const float* __restrict__ bias, unsigned short* __restrict__ gout,
    float* __restrict__ out) {
  __shared__ alignas(16) unsigned short As[2][128 * 64];  // 32 KB
  __shared__ alignas(16) unsigned short Bs[2][128 * 64];  // 32 KB
  const int t = threadIdx.x;
  const int wid = t >> 6, lane = t & 63;
  // bijective XCD-aware swizzle (nwg % 8 == 0 for both launches)
  const int nwg = gridDim.x * gridDim.y;
  const int orig = blockIdx.y * gridDim.x + blockIdx.x;
  const int swz = (orig & 7) * (nwg >> 3) + (orig >> 3);
  const int m0 = (swz / gridDim.x) * 128, n0 = (swz % gridDim.x) * 128;
  const int wm = (wid >> 1) * 64, wn = (wid & 1) * 64;
  const int fr = lane & 15, fq = lane >> 4;
  constexpr int NT = K / 64;
  const int srow = t >> 3;                          // 0..31
  const int ksw = ((t & 7) ^ ((t >> 3) & 7)) << 3;  // pre-swizzled src k-offset (elems)

  auto stageA = [&](int bb, int kt) {
    const unsigned short* s0 = Am + (size_t)(m0 + srow) * K + kt * 64 + ksw;
#pragma unroll
    for (int q = 0; q < 4; ++q)
      gl2lds16(s0 + (size_t)(q * 32) * K, &As[bb][(q * 32 + wid * 8) * 64]);
  };
  auto stageB = [&](int bb, int kt) {
    const unsigned short* s0 = Bm + (size_t)(n0 + srow) * K + kt * 64 + ksw;
#pragma unroll
    for (int q = 0; q < 4; ++q)
      gl2lds16(s0 + (size_t)(q * 32) * K, &Bs[bb][(q * 32 + wid * 8) * 64]);
  };

  // prologue: stage tile0 -> buf0
  stageA(0, 0);
  stageB(0, 0);
  asm volatile("s_waitcnt vmcnt(0)" ::: "memory");
  __builtin_amdgcn_s_barrier();
  __builtin_amdgcn_sched_barrier(0);

  f32x4 acc[4][4] = {};
  for (int c = 0; c < NT; ++c) {
    const int b = c & 1;
    if (c + 1 < NT) {  // issue next-tile staging first
      stageA(b ^ 1, c + 1);
      stageB(b ^ 1, c + 1);
    }
    bf16x8 av[2][4], bv[2][4];
#pragma unroll
    for (int s = 0; s < 2; ++s) {
#pragma unroll
      for (int i = 0; i < 4; ++i)
        av[s][i] =
            *(const bf16x8*)&As[b][(wm + i * 16 + fr) * 64 + ((s * 4 + fq) ^ (fr & 7)) * 8];
#pragma unroll
      for (int j = 0; j < 4; ++j)
        bv[s][j] =
            *(const bf16x8*)&Bs[b][(wn + j * 16 + fr) * 64 + ((s * 4 + fq) ^ (fr & 7)) * 8];
    }
    __builtin_amdgcn_s_setprio(1);
#pragma unroll
    for (int s = 0; s < 2; ++s)
#pragma unroll
      for (int i = 0; i < 4; ++i)
#pragma unroll
        for (int j = 0; j < 4; ++j)
          acc[i][j] =
              __builtin_amdgcn_mfma_f32_16x16x32_bf16(av[s][i], bv[s][j], acc[i][j], 0, 0, 0);
    __builtin_amdgcn_s_setprio(0);
    if (c + 1 < NT) {
      asm volatile("s_waitcnt vmcnt(0)" ::: "memory");  // next tile landed
      __builtin_amdgcn_s_barrier();
      __builtin_amdgcn_sched_barrier(0);  // keep next iter's reads below the barrier
    }
  }

  // epilogue (overlaps the co-resident block's main loop)
#pragma unroll
  for (int i = 0; i < 4; ++i)
#pragma unroll
    for (int j = 0; j < 4; ++j) {
      const int cg = n0 + wn + j * 16 + fr;
      const float bb = bias[cg];
#pragma unroll
      for (int r = 0; r < 4; ++r) {
        const int rg = m0 + wm + i * 16 + fq * 4 + r;
        if (EPI == 0) {
          gout[(size_t)rg * NALL + cg] = f2bf(gelu_fast(acc[i][j][r] + bb));
        } else {
          const size_t off = (size_t)rg * NALL + cg;
          out[off] = out[off] + acc[i][j][r] + bb;
        }
      }
    }
}

extern "C" void kernel_launch(void* const* d_in, const int* in_sizes, int n_in, void* d_out,
                              int out_size, void* d_ws, size_t ws_size, hipStream_t stream) {
  const float* x = (const float*)d_in[0];
  const float* logA = (const float*)d_in[1];
  const float* Bm = (const float*)d_in[2];
  const float* Cm = (const float*)d_in[3];
  const float* Dv = (const float*)d_in[4];
  const float* logdt = (const float*)d_in[5];
  const float* gamma = (const float*)d_in[6];
  const float* beta = (const float*)d_in[7];
  const float* W1 = (const float*)d_in[8];
  const float* b1 = (const float*)d_in[9];
  const float* W2 = (const float*)d_in[10];
  const float* b2 = (const float*)d_in[11];
  float* out = (float*)d_out;

  // workspace layout (bytes). xbf aliases the (later) g region.
  // ends (512 KB, [8][256][64]) aliases the yn region head: ends is dead before
  // y_ln_fused writes yn (scan_fix is the last reader; y_ln runs after).
  char* ws = (char*)d_ws;
  float* mu1 = (float*)(ws + 0);
  float* rstd1 = (float*)(ws + 131072);
  float* gB = (float*)(ws + 524288);
  float* bB = (float*)(ws + 524800);
  unsigned short* Bgt = (unsigned short*)(ws + 525312);   // 64 KB [64][512]
  unsigned short* ctb = (unsigned short*)(ws + 590848);   // 64 KB [512][64]
  unsigned short* w1t = (unsigned short*)(ws + 656384);   // 1 MB  [1024][512]
  unsigned short* w2t = (unsigned short*)(ws + 1704960);  // 1 MB  [512][1024]
  unsigned short* g = (unsigned short*)(ws + 2753536);    // 64 MB [32768][1024]
  unsigned short* xbf = (unsigned short*)(ws + 2753536);  // 32 MB (dead before g written)
  float* xB = (float*)(ws + 69862400);                    // 8 MB [M][64]
  unsigned short* hsb = (unsigned short*)(ws + 78251008); // 4 MB bf16 [M][64]
  unsigned short* yn = (unsigned short*)(ws + 82445312);  // 32 MB bf16
  float* ends = (float*)(ws + 82445312);                  // 512 KB, aliases yn head

  prep_all_kernel<<<280, 256, 0, stream>>>(W1, W2, Cm, Bm, gamma, beta, w1t, w2t, ctb, Bgt, gB,
                                           bB);
  ln_stats_kernel<<<MROWS / 4, 256, 0, stream>>>(x, mu1, rstd1, xbf);
  xb_mfma_kernel<<<MROWS / 128, 256, 0, stream>>>(xbf, Bgt, mu1, rstd1, gB, bB, xB);
  scan_ends_kernel<<<512, 256, 0, stream>>>(xB, logA, logdt, ends);
  scan_fix_kernel<<<512, 256, 0, stream>>>(logA, logdt, ends, xB, hsb);
  y_ln_fused_kernel<<<MROWS / 128, 512, 0, stream>>>(hsb, ctb, x, mu1, rstd1, gamma, beta, Dv,
                                                     out, yn);
  gemm128_kernel<512, 1024, 0><<<dim3(1024 / 128, MROWS / 128), 256, 0, stream>>>(
      yn, w1t, b1, g, nullptr);
  gemm128_kernel<1024, 512, 1><<<dim3(512 / 128, MROWS / 128), 256, 0, stream>>>(
      g, w2t, b2, nullptr, out);
}

// Round 8
// 310.707 us; speedup vs baseline: 1.1712x; 1.1400x over previous
//
#include <hip/hip_runtime.h>
#include <math.h>

#define BATCH 8
#define SEQL 4096
#define DMODEL 512
#define SDIM 64
#define MROWS (BATCH * SEQL)  // 32768
#define LN_EPS 1e-5f

typedef __attribute__((ext_vector_type(8))) short bf16x8;
typedef __attribute__((ext_vector_type(4))) float f32x4;

// ---------- helpers ----------
__device__ __forceinline__ float wave_sum(float v) {
#pragma unroll
  for (int off = 32; off > 0; off >>= 1) v += __shfl_xor(v, off, 64);
  return v;
}

__device__ __forceinline__ unsigned short f2bf(float f) {  // RNE float->bf16
  unsigned int u = __float_as_uint(f);
  u += 0x7fffu + ((u >> 16) & 1u);
  return (unsigned short)(u >> 16);
}

__device__ __forceinline__ float frcp(float x) {  // fast v_rcp (~1e-6 rel err, 1 inst)
  float r;
  asm("v_rcp_f32 %0, %1" : "=v"(r) : "v"(x));
  return r;
}

// fast erf-based gelu (A&S 7.1.26); frcp replaces precise-div (~13 insts -> 1)
__device__ __forceinline__ float gelu_fast(float v) {
  float s = v * 0.70710678118654752f;
  float ax = fabsf(s);
  float t = frcp(1.0f + 0.3275911f * ax);
  float p = ((((1.061405429f * t - 1.453152027f) * t + 1.421413741f) * t - 0.284496736f) * t +
             0.254829592f) *
            t;
  float er = 1.0f - p * __expf(-ax * ax);
  er = copysignf(er, s);
  return 0.5f * v * (1.0f + er);
}

__device__ __forceinline__ void gl2lds16(const void* g, void* l) {
  // async global->LDS, 16B/lane; LDS dest = wave-uniform base + lane*16
  __builtin_amdgcn_global_load_lds((const __attribute__((address_space(1))) void*)g,
                                   (__attribute__((address_space(3))) void*)l, 16, 0, 0);
}

// ---------- K1: LN1 stats for x (mu, rstd per row) + bf16 cast of x ----------
__global__ void ln_stats_kernel(const float* __restrict__ x, float* __restrict__ mu,
                                float* __restrict__ rstd, unsigned short* __restrict__ xbf) {
  int row = blockIdx.x * 4 + (threadIdx.x >> 6);
  int lane = threadIdx.x & 63;
  const float4* xp = (const float4*)(x + (size_t)row * DMODEL);
  float4 a = xp[lane * 2];
  float4 b = xp[lane * 2 + 1];
  float s = a.x + a.y + a.z + a.w + b.x + b.y + b.z + b.w;
  float q = a.x * a.x + a.y * a.y + a.z * a.z + a.w * a.w + b.x * b.x + b.y * b.y +
            b.z * b.z + b.w * b.w;
  s = wave_sum(s);
  q = wave_sum(q);
  uint4 pk;
  pk.x = (unsigned)f2bf(a.x) | ((unsigned)f2bf(a.y) << 16);
  pk.y = (unsigned)f2bf(a.z) | ((unsigned)f2bf(a.w) << 16);
  pk.z = (unsigned)f2bf(b.x) | ((unsigned)f2bf(b.y) << 16);
  pk.w = (unsigned)f2bf(b.z) | ((unsigned)f2bf(b.w) << 16);
  ((uint4*)(xbf + (size_t)row * DMODEL))[lane] = pk;
  if (lane == 0) {
    float m = s * (1.0f / DMODEL);
    float var = q * (1.0f / DMODEL) - m * m;
    mu[row] = m;
    rstd[row] = rsqrtf(var + LN_EPS);
  }
}

// ---------- prep: all weight transposes + B-prep in ONE kernel ----------
__device__ __forceinline__ void transpose_body(const float* __restrict__ W,
                                               unsigned short* __restrict__ Wt, int K, int N,
                                               int bx, int by,
                                               unsigned short (*tile)[65]) {
  int k0 = by * 64, n0 = bx * 64;
  int tx = threadIdx.x & 15, ty = threadIdx.x >> 4;
#pragma unroll
  for (int p = 0; p < 4; ++p) {
    int k = p * 16 + ty;
    float4 v = *(const float4*)&W[(size_t)(k0 + k) * N + n0 + tx * 4];
    tile[tx * 4 + 0][k] = f2bf(v.x);
    tile[tx * 4 + 1][k] = f2bf(v.y);
    tile[tx * 4 + 2][k] = f2bf(v.z);
    tile[tx * 4 + 3][k] = f2bf(v.w);
  }
  __syncthreads();
#pragma unroll
  for (int p = 0; p < 4; ++p) {
    int n = p * 16 + ty;
    ushort4 o;
    o.x = tile[n][tx * 4 + 0];
    o.y = tile[n][tx * 4 + 1];
    o.z = tile[n][tx * 4 + 2];
    o.w = tile[n][tx * 4 + 3];
    *(ushort4*)&Wt[(size_t)(n0 + n) * K + k0 + tx * 4] = o;
  }
}

__global__ __launch_bounds__(256) void prep_all_kernel(
    const float* __restrict__ W1, const float* __restrict__ W2, const float* __restrict__ Cm,
    const float* __restrict__ Bm, const float* __restrict__ gamma,
    const float* __restrict__ beta, unsigned short* __restrict__ w1t,
    unsigned short* __restrict__ w2t, unsigned short* __restrict__ ctb,
    unsigned short* __restrict__ Bgt, float* __restrict__ gB, float* __restrict__ bB) {
  __shared__ unsigned short tile[64][65];
  int b = blockIdx.x;
  if (b < 128) {  // W1 [512][1024] -> w1t [1024][512]
    transpose_body(W1, w1t, 512, 1024, b & 15, b >> 4, tile);
  } else if (b < 256) {  // W2 [1024][512] -> w2t [512][1024]
    transpose_body(W2, w2t, 1024, 512, (b - 128) & 7, (b - 128) >> 3, tile);
  } else if (b < 264) {  // Cm [64][512] -> ctb [512][64]
    transpose_body(Cm, ctb, 64, 512, b - 256, 0, tile);
  } else {  // Bgt[s][d]=bf16(gamma[d]*B[d][s]); gB[s]=gamma@B; bB[s]=beta@B
    int s = (b - 264) * 4 + (threadIdx.x >> 6);
    int l = threadIdx.x & 63;
    float gs = 0.0f, bs = 0.0f;
    unsigned short tmp[8];
#pragma unroll
    for (int u = 0; u < 8; ++u) {
      int d = l * 8 + u;
      float bv = Bm[(size_t)d * SDIM + s];
      float gv = gamma[d], ev = beta[d];
      gs += gv * bv;
      bs += ev * bv;
      tmp[u] = f2bf(gv * bv);
    }
    *(ushort4*)&Bgt[(size_t)s * DMODEL + l * 8] = make_ushort4(tmp[0], tmp[1], tmp[2], tmp[3]);
    *(ushort4*)&Bgt[(size_t)s * DMODEL + l * 8 + 4] =
        make_ushort4(tmp[4], tmp[5], tmp[6], tmp[7]);
    gs = wave_sum(gs);
    bs = wave_sum(bs);
    if (l == 0) {
      gB[s] = gs;
      bB[s] = bs;
    }
  }
}

// ---------- K2: xB = rstd*(xbf@Bgt) - rstd*mu*gB + bB   (MFMA bf16) ----------
__global__ __launch_bounds__(256) void xb_mfma_kernel(
    const unsigned short* __restrict__ xbf, const unsigned short* __restrict__ Bgt,
    const float* __restrict__ mu, const float* __restrict__ rstd, const float* __restrict__ gB,
    const float* __restrict__ bB, float* __restrict__ xB) {
  __shared__ unsigned short As[128 * 32];  // [m][k]
  __shared__ unsigned short Bs[64 * 32];   // [s][k]
  const int t = threadIdx.x;
  const int wave = t >> 6, lane = t & 63;
  const int m0 = blockIdx.x * 128;
  const int wm = wave * 32;
  const int row = t >> 2, seg = t & 3;
  const int fr = lane & 15, fq = lane >> 4;
  f32x4 acc[2][4] = {};
  for (int k0 = 0; k0 < DMODEL; k0 += 32) {
    __syncthreads();
    gl2lds16(xbf + (size_t)(m0 + row) * DMODEL + k0 + seg * 8, As + (size_t)(wave * 16) * 32);
    gl2lds16(xbf + (size_t)(m0 + 64 + row) * DMODEL + k0 + seg * 8,
             As + (size_t)(64 + wave * 16) * 32);
    gl2lds16(Bgt + (size_t)row * DMODEL + k0 + seg * 8, Bs + (size_t)(wave * 16) * 32);
    __syncthreads();
#pragma unroll
    for (int i = 0; i < 2; ++i) {
      bf16x8 a = *(const bf16x8*)&As[(wm + i * 16 + fr) * 32 + fq * 8];
#pragma unroll
      for (int j = 0; j < 4; ++j) {
        bf16x8 b = *(const bf16x8*)&Bs[(j * 16 + fr) * 32 + fq * 8];
        acc[i][j] = __builtin_amdgcn_mfma_f32_16x16x32_bf16(a, b, acc[i][j], 0, 0, 0);
      }
    }
  }
#pragma unroll
  for (int i = 0; i < 2; ++i)
#pragma unroll
    for (int r = 0; r < 4; ++r) {
      const int m = m0 + wm + i * 16 + fq * 4 + r;
      const float rr = rstd[m], negmurr = -mu[m] * rstd[m];
#pragma unroll
      for (int j = 0; j < 4; ++j) {
        const int s = j * 16 + fr;
        xB[(size_t)m * SDIM + s] = rr * acc[i][j][r] + negmurr * gB[s] + bB[s];
      }
    }
}

// ---------- K3: scan, CHUNK=64, carry via wave-parallel Kogge-Stone ----------
// (a) per-chunk local result e_c (zero entry state), TRANSPOSED out: ends_t[b][s][c]
__global__ void scan_ends_kernel(const float* __restrict__ xB, const float* __restrict__ logA,
                                 const float* __restrict__ logdt, float* __restrict__ ends_t) {
  int t = blockIdx.x * 256 + threadIdx.x;
  int s = t & 63;
  int c = (t >> 6) & 63;
  int b = t >> 12;
  float a = expf(-expf(logA[s]) * expf(logdt[0]));
  const float* p = xB + ((size_t)(b * SEQL + c * 64)) * SDIM + s;
  float e = 0.0f;
#pragma unroll
  for (int i = 0; i < 64; ++i) e = a * e + p[(size_t)i * SDIM];
  ends_t[((size_t)(b * 64 + s)) * 64 + c] = e;
}

// (b) one wave per (b,s): weighted inclusive scan over 64 chunk-ends (Kogge-Stone,
// 6 shfl_up steps, multiplier a64^off; a64 is wave-uniform since s is fixed).
// Writes EXCLUSIVE carry H_{c-1} (entry state of chunk c).
__global__ void scan_prefix_kernel(const float* __restrict__ logA,
                                   const float* __restrict__ logdt,
                                   const float* __restrict__ ends_t,
                                   float* __restrict__ carry_t) {
  int wid = threadIdx.x >> 6, lane = threadIdx.x & 63;
  int pair = blockIdx.x * 4 + wid;  // 512 pairs
  int s = pair & 63;
  float a = expf(-expf(logA[s]) * expf(logdt[0]));
  float a64 = a;
#pragma unroll
  for (int i = 0; i < 6; ++i) a64 *= a64;  // a^64
  float x = ends_t[(size_t)pair * 64 + lane];
  float m = a64;
#pragma unroll
  for (int off = 1; off < 64; off <<= 1) {
    float y = __shfl_up(x, off, 64);
    if (lane >= off) x += m * y;
    m = m * m;
  }
  float cy = __shfl_up(x, 1, 64);
  if (lane == 0) cy = 0.0f;
  carry_t[(size_t)pair * 64 + lane] = cy;
}

// (c) final pass: entry state via ONE load, then 64 in-chunk steps.
__global__ void scan_fix_kernel(const float* __restrict__ logA, const float* __restrict__ logdt,
                                const float* __restrict__ carry_t, const float* __restrict__ xB,
                                unsigned short* __restrict__ hsb) {
  int t = blockIdx.x * 256 + threadIdx.x;
  int s = t & 63;
  int c = (t >> 6) & 63;
  int b = t >> 12;
  float a = expf(-expf(logA[s]) * expf(logdt[0]));
  float h = carry_t[((size_t)(b * 64 + s)) * 64 + c];
  const float* p = xB + ((size_t)(b * SEQL + c * 64)) * SDIM + s;
  unsigned short* q = hsb + ((size_t)(b * SEQL + c * 64)) * SDIM + s;
#pragma unroll
  for (int i = 0; i < 64; ++i) {
    h = a * h + p[(size_t)i * SDIM];
    q[(size_t)i * SDIM] = f2bf(h);
  }
}

// ---------- K4: y = hsb@ctb^T + xn*D + x -> out ; then LN(y) -> yn (fused) ----------
// 128 rows x full 512 cols per block, 8 waves (2m x 4n), per-wave 64x128, K=64 one-shot.
__global__ __launch_bounds__(512, 2) void y_ln_fused_kernel(
    const unsigned short* __restrict__ hsb, const unsigned short* __restrict__ ctb,
    const float* __restrict__ x, const float* __restrict__ mu1,
    const float* __restrict__ rstd1, const float* __restrict__ gamma,
    const float* __restrict__ beta, const float* __restrict__ Dv, float* __restrict__ out,
    unsigned short* __restrict__ yn) {
  __shared__ alignas(16) unsigned short As[128 * 64];  // 16 KB, swizzled
  __shared__ alignas(16) unsigned short Bs[512 * 64];  // 64 KB, swizzled
  __shared__ float rsum[128], rsq[128];
  const int t = threadIdx.x;
  const int wid = t >> 6, lane = t & 63;
  const int m0 = blockIdx.x * 128;
  const int wm = (wid >> 2) * 64;   // 0 / 64
  const int wn = (wid & 3) * 128;   // 0..384
  const int fr = lane & 15, fq = lane >> 4;
  const int srow = t >> 3;
  const int ksw = ((t & 7) ^ ((t >> 3) & 7)) << 3;  // pre-swizzled src k-offset
  gl2lds16(hsb + (size_t)(m0 + srow) * 64 + ksw, &As[(wid * 8) * 64]);
  gl2lds16(hsb + (size_t)(m0 + 64 + srow) * 64 + ksw, &As[(64 + wid * 8) * 64]);
#pragma unroll
  for (int h = 0; h < 8; ++h)
    gl2lds16(ctb + (size_t)(h * 64 + srow) * 64 + ksw, &Bs[(h * 64 + wid * 8) * 64]);
  if (t < 128) {
    rsum[t] = 0.0f;
    rsq[t] = 0.0f;
  }
  asm volatile("s_waitcnt vmcnt(0)" ::: "memory");
  __builtin_amdgcn_s_barrier();

  f32x4 acc[4][8] = {};
#pragma unroll
  for (int s = 0; s < 2; ++s) {
    bf16x8 af[4], bf[8];
#pragma unroll
    for (int i = 0; i < 4; ++i)
      af[i] = *(const bf16x8*)&As[(wm + i * 16 + fr) * 64 + ((s * 4 + fq) ^ (fr & 7)) * 8];
#pragma unroll
    for (int j = 0; j < 8; ++j)
      bf[j] = *(const bf16x8*)&Bs[(wn + j * 16 + fr) * 64 + ((s * 4 + fq) ^ (fr & 7)) * 8];
#pragma unroll
    for (int i = 0; i < 4; ++i)
#pragma unroll
      for (int j = 0; j < 8; ++j)
        acc[i][j] = __builtin_amdgcn_mfma_f32_16x16x32_bf16(af[i], bf[j], acc[i][j], 0, 0, 0);
  }

  float ga[8], be[8], dd[8];
#pragma unroll
  for (int j = 0; j < 8; ++j) {
    const int cg = wn + j * 16 + fr;
    ga[j] = gamma[cg];
    be[j] = beta[cg];
    dd[j] = Dv[cg];
  }
  float ps[4][4], pq[4][4];
#pragma unroll
  for (int i = 0; i < 4; ++i)
#pragma unroll
    for (int r = 0; r < 4; ++r) {
      const int m = m0 + wm + i * 16 + fq * 4 + r;
      const float mu = mu1[m], rs = rstd1[m];
      float s1 = 0.0f, s2 = 0.0f;
#pragma unroll
      for (int j = 0; j < 8; ++j) {
        const int cg = wn + j * 16 + fr;
        const float xv = x[(size_t)m * DMODEL + cg];
        float yv = acc[i][j][r] + ((xv - mu) * rs * ga[j] + be[j]) * dd[j] + xv;
        out[(size_t)m * DMODEL + cg] = yv;
        acc[i][j][r] = yv;
        s1 += yv;
        s2 += yv * yv;
      }
      ps[i][r] = s1;
      pq[i][r] = s2;
    }
#pragma unroll
  for (int i = 0; i < 4; ++i)
#pragma unroll
    for (int r = 0; r < 4; ++r) {
#pragma unroll
      for (int off = 1; off < 16; off <<= 1) {
        ps[i][r] += __shfl_xor(ps[i][r], off, 64);
        pq[i][r] += __shfl_xor(pq[i][r], off, 64);
      }
    }
  if (fr == 0) {
#pragma unroll
    for (int i = 0; i < 4; ++i)
#pragma unroll
      for (int r = 0; r < 4; ++r) {
        atomicAdd(&rsum[wm + i * 16 + fq * 4 + r], ps[i][r]);
        atomicAdd(&rsq[wm + i * 16 + fq * 4 + r], pq[i][r]);
      }
  }
  __syncthreads();
#pragma unroll
  for (int i = 0; i < 4; ++i)
#pragma unroll
    for (int r = 0; r < 4; ++r) {
      const int rl = wm + i * 16 + fq * 4 + r;
      const int m = m0 + rl;
      const float mu2 = rsum[rl] * (1.0f / DMODEL);
      const float var = rsq[rl] * (1.0f / DMODEL) - mu2 * mu2;
      const float rs2 = rsqrtf(var + LN_EPS);
#pragma unroll
      for (int j = 0; j < 8; ++j) {
        const int cg = wn + j * 16 + fr;
        yn[(size_t)m * DMODEL + cg] = f2bf((acc[i][j][r] - mu2) * rs2 * ga[j] + be[j]);
      }
    }
}

// ---------- 128x128-tile, BK=64, 4-wave, double-buffered, 2 blocks/CU GEMM ----------
// (R4 config: best measured MLP GEMM.)
template <int K, int NALL, int EPI>
__global__ __launch_bounds__(256, 2) void gemm128_kernel(
    const unsigned short* __restrict__ Am, const unsigned short* __restrict__ Bm,
    const float* __restrict__ bias, unsigned short* __restrict__ gout,
    float* __restrict__ out) {
  __shared__ alignas(16) unsigned short As[2][128 * 64];  // 32 KB
  __shared__ alignas(16) unsigned short Bs[2][128 * 64];  // 32 KB
  const int t = threadIdx.x;
  const int wid = t >> 6, lane = t & 63;
  // bijective XCD-aware swizzle (nwg % 8 == 0 for both launches)
  const int nwg = gridDim.x * gridDim.y;
  const int orig = blockIdx.y * gridDim.x + blockIdx.x;
  const int swz = (orig & 7) * (nwg >> 3) + (orig >> 3);
  const int m0 = (swz / gridDim.x) * 128, n0 = (swz % gridDim.x) * 128;
  const int wm = (wid >> 1) * 64, wn = (wid & 1) * 64;
  const int fr = lane & 15, fq = lane >> 4;
  constexpr int NT = K / 64;
  const int srow = t >> 3;                          // 0..31
  const int ksw = ((t & 7) ^ ((t >> 3) & 7)) << 3;  // pre-swizzled src k-offset (elems)

  auto stageA = [&](int bb, int kt) {
    const unsigned short* s0 = Am + (size_t)(m0 + srow) * K + kt * 64 + ksw;
#pragma unroll
    for (int q = 0; q < 4; ++q)
      gl2lds16(s0 + (size_t)(q * 32) * K, &As[bb][(q * 32 + wid * 8) * 64]);
  };
  auto stageB = [&](int bb, int kt) {
    const unsigned short* s0 = Bm + (size_t)(n0 + srow) * K + kt * 64 + ksw;
#pragma unroll
    for (int q = 0; q < 4; ++q)
      gl2lds16(s0 + (size_t)(q * 32) * K, &Bs[bb][(q * 32 + wid * 8) * 64]);
  };

  // prologue: stage tile0 -> buf0
  stageA(0, 0);
  stageB(0, 0);
  asm volatile("s_waitcnt vmcnt(0)" ::: "memory");
  __builtin_amdgcn_s_barrier();
  __builtin_amdgcn_sched_barrier(0);

  f32x4 acc[4][4] = {};
  for (int c = 0; c < NT; ++c) {
    const int b = c & 1;
    if (c + 1 < NT) {  // issue next-tile staging first
      stageA(b ^ 1, c + 1);
      stageB(b ^ 1, c + 1);
    }
    bf16x8 av[2][4], bv[2][4];
#pragma unroll
    for (int s = 0; s < 2; ++s) {
#pragma unroll
      for (int i = 0; i < 4; ++i)
        av[s][i] =
            *(const bf16x8*)&As[b][(wm + i * 16 + fr) * 64 + ((s * 4 + fq) ^ (fr & 7)) * 8];
#pragma unroll
      for (int j = 0; j < 4; ++j)
        bv[s][j] =
            *(const bf16x8*)&Bs[b][(wn + j * 16 + fr) * 64 + ((s * 4 + fq) ^ (fr & 7)) * 8];
    }
    __builtin_amdgcn_s_setprio(1);
#pragma unroll
    for (int s = 0; s < 2; ++s)
#pragma unroll
      for (int i = 0; i < 4; ++i)
#pragma unroll
        for (int j = 0; j < 4; ++j)
          acc[i][j] =
              __builtin_amdgcn_mfma_f32_16x16x32_bf16(av[s][i], bv[s][j], acc[i][j], 0, 0, 0);
    __builtin_amdgcn_s_setprio(0);
    if (c + 1 < NT) {
      asm volatile("s_waitcnt vmcnt(0)" ::: "memory");  // next tile landed
      __builtin_amdgcn_s_barrier();
      __builtin_amdgcn_sched_barrier(0);  // keep next iter's reads below the barrier
    }
  }

  // epilogue (overlaps the co-resident block's main loop)
#pragma unroll
  for (int i = 0; i < 4; ++i)
#pragma unroll
    for (int j = 0; j < 4; ++j) {
      const int cg = n0 + wn + j * 16 + fr;
      const float bb = bias[cg];
#pragma unroll
      for (int r = 0; r < 4; ++r) {
        const int rg = m0 + wm + i * 16 + fq * 4 + r;
        if (EPI == 0) {
          gout[(size_t)rg * NALL + cg] = f2bf(gelu_fast(acc[i][j][r] + bb));
        } else {
          const size_t off = (size_t)rg * NALL + cg;
          out[off] = out[off] + acc[i][j][r] + bb;
        }
      }
    }
}

extern "C" void kernel_launch(void* const* d_in, const int* in_sizes, int n_in, void* d_out,
                              int out_size, void* d_ws, size_t ws_size, hipStream_t stream) {
  const float* x = (const float*)d_in[0];
  const float* logA = (const float*)d_in[1];
  const float* Bm = (const float*)d_in[2];
  const float* Cm = (const float*)d_in[3];
  const float* Dv = (const float*)d_in[4];
  const float* logdt = (const float*)d_in[5];
  const float* gamma = (const float*)d_in[6];
  const float* beta = (const float*)d_in[7];
  const float* W1 = (const float*)d_in[8];
  const float* b1 = (const float*)d_in[9];
  const float* W2 = (const float*)d_in[10];
  const float* b2 = (const float*)d_in[11];
  float* out = (float*)d_out;

  // workspace layout (bytes). xbf aliases the (later) g region.
  char* ws = (char*)d_ws;
  float* mu1 = (float*)(ws + 0);
  float* rstd1 = (float*)(ws + 131072);
  float* ends_t = (float*)(ws + 262144);                  // 128 KB [512][64]
  float* carry_t = (float*)(ws + 393216);                 // 128 KB [512][64]
  float* gB = (float*)(ws + 524288);
  float* bB = (float*)(ws + 524800);
  unsigned short* Bgt = (unsigned short*)(ws + 525312);   // 64 KB [64][512]
  unsigned short* ctb = (unsigned short*)(ws + 590848);   // 64 KB [512][64]
  unsigned short* w1t = (unsigned short*)(ws + 656384);   // 1 MB  [1024][512]
  unsigned short* w2t = (unsigned short*)(ws + 1704960);  // 1 MB  [512][1024]
  unsigned short* g = (unsigned short*)(ws + 2753536);    // 64 MB [32768][1024]
  unsigned short* xbf = (unsigned short*)(ws + 2753536);  // 32 MB (dead before g written)
  float* xB = (float*)(ws + 69862400);                    // 8 MB [M][64]
  unsigned short* hsb = (unsigned short*)(ws + 78251008); // 4 MB bf16 [M][64]
  unsigned short* yn = (unsigned short*)(ws + 82445312);  // 32 MB bf16

  prep_all_kernel<<<280, 256, 0, stream>>>(W1, W2, Cm, Bm, gamma, beta, w1t, w2t, ctb, Bgt, gB,
                                           bB);
  ln_stats_kernel<<<MROWS / 4, 256, 0, stream>>>(x, mu1, rstd1, xbf);
  xb_mfma_kernel<<<MROWS / 128, 256, 0, stream>>>(xbf, Bgt, mu1, rstd1, gB, bB, xB);
  scan_ends_kernel<<<128, 256, 0, stream>>>(xB, logA, logdt, ends_t);
  scan_prefix_kernel<<<128, 256, 0, stream>>>(logA, logdt, ends_t, carry_t);
  scan_fix_kernel<<<128, 256, 0, stream>>>(logA, logdt, carry_t, xB, hsb);
  y_ln_fused_kernel<<<MROWS / 128, 512, 0, stream>>>(hsb, ctb, x, mu1, rstd1, gamma, beta, Dv,
                                                     out, yn);
  gemm128_kernel<512, 1024, 0><<<dim3(1024 / 128, MROWS / 128), 256, 0, stream>>>(
      yn, w1t, b1, g, nullptr);
  gemm128_kernel<1024, 512, 1><<<dim3(512 / 128, MROWS / 128), 256, 0, stream>>>(
      g, w2t, b2, nullptr, out);
}